// Round 7
// baseline (282.204 us; speedup 1.0000x reference)
//
#include <hip/hip_runtime.h>

// Problem constants (from reference)
#define CC 9605
#define BB 2048
#define LL 8
#define TPB 1024
#define NWAVE 16
#define CAND_MAX 384
#define NEGF (-1e30f)

// d_ws layout (unsigned words):
//   wsu[0] = wl entry count (atomic)
//   wsu[1] = dtype sniff flags (atomic OR)
//   wsu[4 .. 4+2048) = whitelist entries (col<<8 | mask)
//   byte offset 16384: float partials[BB]
#define WS_PARTIALS_OFF 16384

__device__ __forceinline__ unsigned enc_f(float f) {
  unsigned u = __float_as_uint(f);
  return (u & 0x80000000u) ? ~u : (u | 0x80000000u);
}
__device__ __forceinline__ float dec_u(unsigned e) {
  unsigned u = (e & 0x80000000u) ? (e & 0x7fffffffu) : ~e;
  return __uint_as_float(u);
}
__device__ __forceinline__ float sigm(float z) {
  return 1.0f / (1.0f + __expf(-z));
}

// ---- dtype sniff (word loads): byte signatures over the raw wl buffer ----
//   u8  : byte==1 at offsets %4 != 0        -> flag 1 (and 2)
//   i32 : byte==1 only at offsets %4 == 0   -> flag 2
//   f32 : 0x3f at %4==3, never byte==1      -> flag 8
//   bf16: 0x3f at odd offsets incl %4==1    -> flag 4 (and 8)
__global__ void wl_sniff(const unsigned* __restrict__ wlw,
                         unsigned* __restrict__ wsu) {
  const int nwords = (LL * CC) / 4;  // 76840 % 4 == 0
  const int stride = gridDim.x * blockDim.x;
  unsigned f = 0u;
  for (int j = blockIdx.x * blockDim.x + threadIdx.x; j < nwords; j += stride) {
    unsigned w = wlw[j];
#pragma unroll
    for (int k = 0; k < 4; ++k) {
      unsigned b = (w >> (8 * k)) & 255u;
      if (b == 1u)    { f |= 2u; if (k != 0) f |= 1u; }
      if (b == 0x3fu) { f |= 8u; if (k == 1) f |= 4u; }
    }
  }
#pragma unroll
  for (int off = 32; off >= 1; off >>= 1) f |= __shfl_xor(f, off, 64);
  if ((threadIdx.x & 63) == 0 && f) atomicOr(&wsu[1], f);
}

__global__ void wl_compact(const unsigned char* __restrict__ wl,
                           unsigned* __restrict__ wsu) {
  const int tid = threadIdx.x;
  const int lane = tid & 63;
  const int c = blockIdx.x * 256 + tid;
  const unsigned g = wsu[1];
  const int dt = (g & 1u) ? 0 : (g & 4u) ? 3 : (g & 2u) ? 1 : (g & 8u) ? 2 : 0;
  const int* wl32 = (const int*)wl;
  const float* wlf = (const float*)wl;
  const unsigned short* wlh = (const unsigned short*)wl;
  unsigned m = 0u;
  if (c < CC) {
#pragma unroll
    for (int l = 0; l < LL; ++l) {
      int j = l * CC + c;
      bool on;
      if (dt == 0) on = (wl[j] != 0);
      else if (dt == 1) on = (wl32[j] != 0);
      else if (dt == 2) on = (wlf[j] != 0.0f);
      else on = (wlh[j] != 0);
      if (on) m |= (1u << l);
    }
  }
  unsigned long long bal = __ballot(m != 0u);
  if (bal) {
    unsigned wcnt = (unsigned)__popcll(bal);
    unsigned basep = 0u;
    if (lane == 0) basep = atomicAdd(&wsu[0], wcnt);
    basep = __shfl(basep, 0, 64);
    if (m) {
      unsigned pos = basep + (unsigned)__popcll(bal & ((1ull << lane) - 1ull));
      if (pos < 2048u) wsu[4 + pos] = ((unsigned)c << 8) | m;
    }
  }
}

__global__ __launch_bounds__(TPB) void loss_kernel(
    const float* __restrict__ x, const float* __restrict__ y,
    const unsigned* __restrict__ wsu, float* __restrict__ partials) {
  __shared__ unsigned sh_cand[CAND_MAX];
  __shared__ unsigned sh_redM[NWAVE];
  __shared__ unsigned sh_redC[NWAVE];
  __shared__ unsigned sh_cnt;
  __shared__ unsigned sh_e11;
  __shared__ float sh_wl[NWAVE][9];

  const int tid = threadIdx.x;
  const int lane = tid & 63;
  const int wid = tid >> 6;
  const int b = blockIdx.x;
  const long long base = (long long)b * CC;

  // ---- 1a. row loads: 3 independent float4 per thread (all in flight) ----
  const int soff = (4 - (b & 3)) & 3;          // (b*9605 + soff) % 4 == 0
  const int ngroups = (CC - soff) >> 2;        // 2400 or 2401
  const int tailn = CC - soff - (ngroups << 2);
  const int m_extra = soff + tailn;            // <= 6 scalar leftovers
  const float4* vp = (const float4*)(x + base + soff);  // 16B aligned
  const float4 t0 = vp[tid];                   // tid   <= 1023 < 2400
  const float4 t1 = vp[tid + 1024];            // <= 2047 < 2400
  const int g2 = tid + 2048;
  const bool hg2 = (g2 < ngroups);
  float4 t2;
  if (hg2) t2 = vp[g2];
  float tailv = 0.0f;
  if (tid < m_extra) {
    int col = (tid < soff) ? tid : (soff + (ngroups << 2) + (tid - soff));
    tailv = x[base + col];
  }

  // ---- 1b. whitelist gather loads (one entry per thread; nu ~290) ----
  const unsigned nu = wsu[0];
  const unsigned* ents = wsu + 4;
  const bool h0 = (unsigned)tid < nu;
  unsigned ent0 = 0u;
  float gx0 = NEGF, gy0 = 0.0f;
  if (h0) {
    ent0 = ents[tid];
    gx0 = x[base + (ent0 >> 8)];
    gy0 = y[base + (ent0 >> 8)];
  }

  // ---- 1c. encode into 13 registers ----
  unsigned enc[13];
  enc[0] = enc_f(t0.x); enc[1] = enc_f(t0.y);
  enc[2] = enc_f(t0.z); enc[3] = enc_f(t0.w);
  enc[4] = enc_f(t1.x); enc[5] = enc_f(t1.y);
  enc[6] = enc_f(t1.z); enc[7] = enc_f(t1.w);
  if (hg2) {
    enc[8] = enc_f(t2.x); enc[9] = enc_f(t2.y);
    enc[10] = enc_f(t2.z); enc[11] = enc_f(t2.w);
  } else {
    enc[8] = 0u; enc[9] = 0u; enc[10] = 0u; enc[11] = 0u;  // pad < T (T>=1)
  }
  enc[12] = (tid < m_extra) ? enc_f(tailv) : 0u;
  if (tid == 0) sh_cnt = 0u;

  // ---- 2. block max ----
  unsigned mx = 0u;
#pragma unroll
  for (int i = 0; i < 13; ++i) mx = max(mx, enc[i]);
#pragma unroll
  for (int off = 32; off >= 1; off >>= 1) mx = max(mx, __shfl_xor(mx, off, 64));
  if (lane == 0) sh_redM[wid] = mx;
  __syncthreads();
  unsigned Emax = 0u;
#pragma unroll
  for (int w = 0; w < NWAVE; ++w) Emax = max(Emax, sh_redM[w]);

  // block count of enc >= T, all-register (uniform result on all threads)
  auto blk_count = [&](unsigned T) -> unsigned {
    unsigned cnt = 0u;
#pragma unroll
    for (int i = 0; i < 13; ++i) cnt += (enc[i] >= T) ? 1u : 0u;
#pragma unroll
    for (int off = 32; off >= 1; off >>= 1) cnt += __shfl_xor(cnt, off, 64);
    __syncthreads();                            // guard sh_redC reuse
    if (lane == 0) sh_redC[wid] = cnt;
    __syncthreads();
    unsigned s = 0u;
#pragma unroll
    for (int w = 0; w < NWAVE; ++w) s += sh_redC[w];
    return s;
  };

  // ---- 3. find window [lo,...) holding rank 11 (probes are ~free now) ----
  const unsigned STEP = 1u << 22;  // ~ divide-by-sqrt(2) per step
  unsigned E11 = 0u;
  bool done = false;
  unsigned lo = (Emax > STEP) ? (Emax - STEP) : 1u;
  unsigned hi = Emax + 1u;
  unsigned c = blk_count(lo);
  while (c < 11u && lo > 1u) {
    hi = lo;
    lo = (lo > STEP) ? (lo - STEP) : 1u;
    c = blk_count(lo);
  }
  while (c > CAND_MAX) {  // rare: bisect (tie-collapse => exact answer)
    if (hi - lo <= 1u) { E11 = lo; done = true; break; }
    unsigned mid = lo + ((hi - lo) >> 1);
    unsigned cm = blk_count(mid);
    if (cm >= 11u) { lo = mid; c = cm; } else { hi = mid; }
  }

  // ---- 4. ballot-compact candidates (>= lo) from registers ----
  if (!done) {
#pragma unroll
    for (int i = 0; i < 13; ++i) {
      bool pr = (enc[i] >= lo);
      unsigned long long bal = __ballot(pr);
      if (bal) {
        unsigned wcnt = (unsigned)__popcll(bal);
        unsigned basep = 0u;
        if (lane == 0) basep = atomicAdd(&sh_cnt, wcnt);
        basep = __shfl(basep, 0, 64);
        if (pr) {
          unsigned posn =
              basep + (unsigned)__popcll(bal & ((1ull << lane) - 1ull));
          sh_cand[posn] = enc[i];
        }
      }
    }
    __syncthreads();

    // ---- 5. single-wave register top-11 ----
    if (wid == 0) {
      unsigned v0[6];                           // 6*64 = 384 = CAND_MAX
#pragma unroll
      for (int j = 0; j < 6; ++j) {
        unsigned idx = (unsigned)lane + 64u * j;
        v0[j] = (idx < c) ? sh_cand[idx] : 0u;
      }
      unsigned ans = 0u;
      for (int r = 0; r < 11; ++r) {
        unsigned lmx = v0[0];
#pragma unroll
        for (int j = 1; j < 6; ++j) lmx = max(lmx, v0[j]);
        unsigned wm = lmx;
#pragma unroll
        for (int off = 32; off >= 1; off >>= 1)
          wm = max(wm, __shfl_xor(wm, off, 64));
        ans = wm;
        if (r < 10) {
          unsigned long long bal = __ballot(lmx == wm);
          int first = (int)__ffsll((long long)bal) - 1;
          if (lane == first) {  // remove ONE instance of wm
            bool rm = false;
#pragma unroll
            for (int j = 0; j < 6; ++j) {
              if (!rm && v0[j] == wm) { v0[j] = 0u; rm = true; }
            }
          }
        }
      }
      if (lane == 0) sh_e11 = ans;
    }
    __syncthreads();
    E11 = sh_e11;
  }

  // ---- 6. whitelist gather accumulate + block reduce ----
  float lm[8];
#pragma unroll
  for (int l = 0; l < 8; ++l) lm[l] = NEGF;
  unsigned pmask = 0u;  // bits0-7: label present; bits8-15: label has positive
  if (h0) {
    unsigned mk = ent0 & 255u;
    pmask |= mk;
    if (gy0 > 0.0f) pmask |= (mk << 8);
#pragma unroll
    for (int l = 0; l < 8; ++l)
      if ((mk >> l) & 1u) lm[l] = fmaxf(lm[l], gx0);
  }
  // safety net for nu > 1024 (never hit at this problem's sparsity)
  for (unsigned e = (unsigned)tid + 1024u; e < nu; e += 1024u) {
    unsigned ent = ents[e];
    unsigned mk = ent & 255u;
    float xv = x[base + (ent >> 8)];
    float yv = y[base + (ent >> 8)];
    pmask |= mk;
    if (yv > 0.0f) pmask |= (mk << 8);
#pragma unroll
    for (int l = 0; l < 8; ++l)
      if ((mk >> l) & 1u) lm[l] = fmaxf(lm[l], xv);
  }
#pragma unroll
  for (int off = 32; off >= 1; off >>= 1) {
    pmask |= __shfl_xor(pmask, off, 64);
#pragma unroll
    for (int l = 0; l < 8; ++l) lm[l] = fmaxf(lm[l], __shfl_xor(lm[l], off, 64));
  }
  if (lane == 0) {
#pragma unroll
    for (int l = 0; l < 8; ++l) sh_wl[wid][l] = lm[l];
    sh_wl[wid][8] = __uint_as_float(pmask);
  }
  __syncthreads();

  // ---- 7. epilogue on thread 0: per-row partial ----
  if (tid == 0) {
    float LM[8];
    unsigned PM = 0u;
#pragma unroll
    for (int l = 0; l < 8; ++l) LM[l] = NEGF;
    for (int w = 0; w < NWAVE; ++w) {
#pragma unroll
      for (int l = 0; l < 8; ++l) LM[l] = fmaxf(LM[l], sh_wl[w][l]);
      PM |= __float_as_uint(sh_wl[w][8]);
    }
    unsigned PR = PM & 255u, PO = (PM >> 8) & 255u;
    float thres = fmaxf(sigm(dec_u(E11)), 0.5f);
    float cmax = NEGF, imax = NEGF, umax = NEGF;
#pragma unroll
    for (int l = 0; l < 8; ++l) {
      if ((PR >> l) & 1u) {
        float ml = sigm(LM[l]);
        umax = fmaxf(umax, ml);
        if ((PO >> l) & 1u) cmax = fmaxf(cmax, ml);
        else imax = fmaxf(imax, ml);
      }
    }
    bool anyc = (PO != 0u);
    bool anyi = (PO != 255u);  // L == 8 labels always exist
    float x1 = anyc ? cmax : thres;
    float x2 = anyc ? (anyi ? fmaxf(imax, thres) : thres)
                    : ((nu > 0u) ? umax : NEGF);
    float coef = anyc ? 1.0f : 0.5f;
    float dd = x2 - x1 + 0.1f;
    float rank = ((dd > 0.0f) ? 2.0f : 1.0f) * sigm(10.0f * dd);
    partials[b] = coef * rank;
  }
}

__global__ void final_reduce(const float* __restrict__ partials,
                             float* __restrict__ out) {
  __shared__ float sh[4];
  const int tid = threadIdx.x;
  const int lane = tid & 63;
  const int wid = tid >> 6;
  float s = 0.0f;
  for (int i = tid; i < BB; i += 256) s += partials[i];
#pragma unroll
  for (int off = 32; off >= 1; off >>= 1) s += __shfl_xor(s, off, 64);
  if (lane == 0) sh[wid] = s;
  __syncthreads();
  if (tid == 0) out[0] = (sh[0] + sh[1] + sh[2] + sh[3]) * (1.0f / (float)BB);
}

extern "C" void kernel_launch(void* const* d_in, const int* in_sizes, int n_in,
                              void* d_out, int out_size, void* d_ws,
                              size_t ws_size, hipStream_t stream) {
  const float* x = (const float*)d_in[0];
  const float* y = (const float*)d_in[1];
  // d_in[2] (y_neg) is faithfully ignored — it never affects the loss.
  const unsigned char* wl = (const unsigned char*)d_in[3];
  float* out = (float*)d_out;
  unsigned* wsu = (unsigned*)d_ws;
  float* partials = (float*)((char*)d_ws + WS_PARTIALS_OFF);

  hipMemsetAsync(d_ws, 0, 16, stream);  // zero wsu[0..3]
  wl_sniff<<<64, 256, 0, stream>>>((const unsigned*)wl, wsu);
  wl_compact<<<(CC + 255) / 256, 256, 0, stream>>>(wl, wsu);
  loss_kernel<<<BB, TPB, 0, stream>>>(x, y, wsu, partials);
  final_reduce<<<1, 256, 0, stream>>>(partials, out);
}

// Round 8
// 238.666 us; speedup vs baseline: 1.1824x; 1.1824x over previous
//
#include <hip/hip_runtime.h>

// Problem constants (from reference)
#define CC 9605
#define BB 2048
#define LL 8
#define CAND_MAX 384
#define NEGF (-1e30f)

// d_ws layout (unsigned words):
//   wsu[0] = wl entry count (atomic)
//   wsu[1] = dtype sniff flags (atomic OR)
//   wsu[4 .. 4+2048) = whitelist entries (col<<8 | mask)
//   byte offset 16384: float partials[BB]
#define WS_PARTIALS_OFF 16384

__device__ __forceinline__ unsigned enc_f(float f) {
  unsigned u = __float_as_uint(f);
  return (u & 0x80000000u) ? ~u : (u | 0x80000000u);
}
__device__ __forceinline__ float dec_u(unsigned e) {
  unsigned u = (e & 0x80000000u) ? (e & 0x7fffffffu) : ~e;
  return __uint_as_float(u);
}
__device__ __forceinline__ float sigm(float z) {
  return 1.0f / (1.0f + __expf(-z));
}

// async global->LDS DMA, 16B per lane; lds ptr must be wave-uniform
// (HW writes lane i to ldsbase + i*16) [guide §5: width=16 verified m97]
__device__ __forceinline__ void gload_lds16(const void* g, void* l) {
  __builtin_amdgcn_global_load_lds(
      (const __attribute__((address_space(1))) unsigned*)g,
      (__attribute__((address_space(3))) unsigned*)l, 16, 0, 0);
}

// ---- dtype sniff (word loads): byte signatures over the raw wl buffer ----
//   u8  : byte==1 at offsets %4 != 0        -> flag 1 (and 2)
//   i32 : byte==1 only at offsets %4 == 0   -> flag 2
//   f32 : 0x3f at %4==3, never byte==1      -> flag 8
//   bf16: 0x3f at odd offsets incl %4==1    -> flag 4 (and 8)
__global__ void wl_sniff(const unsigned* __restrict__ wlw,
                         unsigned* __restrict__ wsu) {
  const int nwords = (LL * CC) / 4;  // 76840 % 4 == 0
  const int stride = gridDim.x * blockDim.x;
  unsigned f = 0u;
  for (int j = blockIdx.x * blockDim.x + threadIdx.x; j < nwords; j += stride) {
    unsigned w = wlw[j];
#pragma unroll
    for (int k = 0; k < 4; ++k) {
      unsigned b = (w >> (8 * k)) & 255u;
      if (b == 1u)    { f |= 2u; if (k != 0) f |= 1u; }
      if (b == 0x3fu) { f |= 8u; if (k == 1) f |= 4u; }
    }
  }
#pragma unroll
  for (int off = 32; off >= 1; off >>= 1) f |= __shfl_xor(f, off, 64);
  if ((threadIdx.x & 63) == 0 && f) atomicOr(&wsu[1], f);
}

__global__ void wl_compact(const unsigned char* __restrict__ wl,
                           unsigned* __restrict__ wsu) {
  const int tid = threadIdx.x;
  const int lane = tid & 63;
  const int c = blockIdx.x * 256 + tid;
  const unsigned g = wsu[1];
  const int dt = (g & 1u) ? 0 : (g & 4u) ? 3 : (g & 2u) ? 1 : (g & 8u) ? 2 : 0;
  const int* wl32 = (const int*)wl;
  const float* wlf = (const float*)wl;
  const unsigned short* wlh = (const unsigned short*)wl;
  unsigned m = 0u;
  if (c < CC) {
#pragma unroll
    for (int l = 0; l < LL; ++l) {
      int j = l * CC + c;
      bool on;
      if (dt == 0) on = (wl[j] != 0);
      else if (dt == 1) on = (wl32[j] != 0);
      else if (dt == 2) on = (wlf[j] != 0.0f);
      else on = (wlh[j] != 0);
      if (on) m |= (1u << l);
    }
  }
  unsigned long long bal = __ballot(m != 0u);
  if (bal) {
    unsigned wcnt = (unsigned)__popcll(bal);
    unsigned basep = 0u;
    if (lane == 0) basep = atomicAdd(&wsu[0], wcnt);
    basep = __shfl(basep, 0, 64);
    if (m) {
      unsigned pos = basep + (unsigned)__popcll(bal & ((1ull << lane) - 1ull));
      if (pos < 2048u) wsu[4 + pos] = ((unsigned)c << 8) | m;
    }
  }
}

__global__ __launch_bounds__(256, 4) void loss_kernel(
    const float* __restrict__ x, const float* __restrict__ y,
    const unsigned* __restrict__ wsu, float* __restrict__ partials) {
  __shared__ __align__(16) float sh_row[9608];   // 2402 float4 (row + pad)
  __shared__ unsigned sh_cand[CAND_MAX];
  __shared__ unsigned sh_redM[4];
  __shared__ unsigned sh_redC[4];
  __shared__ unsigned sh_cnt;
  __shared__ unsigned sh_e11;
  __shared__ float sh_wl[4][10];

  const int tid = threadIdx.x;
  const int lane = tid & 63;
  const int wid = tid >> 6;
  const int b = blockIdx.x;
  const long long base = (long long)b * CC;

  const int soff = (4 - (b & 3)) & 3;          // (b*9605 + soff) % 4 == 0
  const int ngroups = (CC - soff) >> 2;        // 2400 or 2401
  const int tailn = CC - soff - (ngroups << 2);
  const int m_extra = soff + tailn;            // <= 6 scalar leftovers
  const float4* vp = (const float4*)(x + base + soff);  // 16B aligned

  // ---- 1a. tail scalar loads FIRST (their waitcnt won't drain the DMAs) ----
  float tailv = 0.0f;
  if (tid < m_extra) {
    int col = (tid < soff) ? tid : (soff + (ngroups << 2) + (tid - soff));
    tailv = x[base + col];
  }

  // ---- 1b. whitelist gather loads (overlap the DMA + selection) ----
  const unsigned nu = wsu[0];
  const unsigned* ents = wsu + 4;
  const bool h0 = (unsigned)tid < nu;
  const bool h1 = (unsigned)(tid + 256) < nu;
  unsigned ent0 = 0u, ent1 = 0u;
  float gx0 = NEGF, gy0 = 0.0f, gx1 = NEGF, gy1 = 0.0f;
  if (h0) ent0 = ents[tid];
  if (h1) ent1 = ents[tid + 256];
  if (h0) { gx0 = x[base + (ent0 >> 8)]; gy0 = y[base + (ent0 >> 8)]; }
  if (h1) { gx1 = x[base + (ent1 >> 8)]; gy1 = y[base + (ent1 >> 8)]; }

  // ---- 1c. row -> LDS via async DMA (zero VGPR footprint, all in flight) ---
  float4* rv = (float4*)sh_row;
#pragma unroll
  for (int i = 0; i < 9; ++i) {                // groups 0..2303 < 2400: safe
    const int gbase = (i << 8) + (wid << 6);   // wave-uniform
    gload_lds16(&vp[gbase + lane], &rv[gbase]);
  }
  {
    const int g9 = (9 << 8) + tid;
    const int gbase = (9 << 8) + (wid << 6);   // uniform; HW adds lane*16
    if (g9 < ngroups) gload_lds16(&vp[g9], &rv[gbase]);
  }
  // tail + pad written via LDS stores (disjoint from DMA byte range)
  if (tid < m_extra) sh_row[(ngroups << 2) + tid] = tailv;
  if (tid < 3) sh_row[9605 + tid] = NEGF;
  if (tid == 0) sh_cnt = 0u;
  __syncthreads();  // compiler drains vmcnt(0) here: DMA + gathers complete

  // ---- 2. block max (encode at read time) ----
  unsigned mx = 0u;
#pragma unroll
  for (int i = 0; i < 10; ++i) {
    int g = tid + (i << 8);
    if (g < 2402) {
      float4 v = rv[g];
      mx = max(mx, max(max(enc_f(v.x), enc_f(v.y)),
                       max(enc_f(v.z), enc_f(v.w))));
    }
  }
#pragma unroll
  for (int off = 32; off >= 1; off >>= 1) mx = max(mx, __shfl_xor(mx, off, 64));
  if (lane == 0) sh_redM[wid] = mx;
  __syncthreads();
  const unsigned Emax =
      max(max(sh_redM[0], sh_redM[1]), max(sh_redM[2], sh_redM[3]));

  // block count of enc(row) >= T (uniform result on all threads)
  auto blk_count = [&](unsigned T) -> unsigned {
    unsigned cnt = 0u;
#pragma unroll
    for (int i = 0; i < 10; ++i) {
      int g = tid + (i << 8);
      if (g < 2402) {
        float4 v = rv[g];
        cnt += (enc_f(v.x) >= T) + (enc_f(v.y) >= T) +
               (enc_f(v.z) >= T) + (enc_f(v.w) >= T);
      }
    }
#pragma unroll
    for (int off = 32; off >= 1; off >>= 1) cnt += __shfl_xor(cnt, off, 64);
    __syncthreads();                            // guard sh_redC reuse
    if (lane == 0) sh_redC[wid] = cnt;
    __syncthreads();
    return sh_redC[0] + sh_redC[1] + sh_redC[2] + sh_redC[3];
  };

  // ---- 3. find window [lo,...) holding rank 11 (typ. 1 probe) ----
  const unsigned STEP = 1u << 22;
  unsigned E11 = 0u;
  bool done = false;
  unsigned lo = (Emax > STEP) ? (Emax - STEP) : 1u;
  unsigned hi = Emax + 1u;
  unsigned c = blk_count(lo);
  while (c < 11u && lo > 1u) {
    hi = lo;
    lo = (lo > STEP) ? (lo - STEP) : 1u;
    c = blk_count(lo);
  }
  while (c > CAND_MAX) {  // rare: bisect (tie-collapse => exact answer)
    if (hi - lo <= 1u) { E11 = lo; done = true; break; }
    unsigned mid = lo + ((hi - lo) >> 1);
    unsigned cm = blk_count(mid);
    if (cm >= 11u) { lo = mid; c = cm; } else { hi = mid; }
  }

  // ---- 4. ballot-compact candidates (>= lo) into sh_cand ----
  if (!done) {
#pragma unroll
    for (int i = 0; i < 10; ++i) {
      int g = tid + (i << 8);
      unsigned vals[4] = {0u, 0u, 0u, 0u};
      if (g < 2402) {
        float4 v = rv[g];
        vals[0] = enc_f(v.x); vals[1] = enc_f(v.y);
        vals[2] = enc_f(v.z); vals[3] = enc_f(v.w);
      }
#pragma unroll
      for (int k = 0; k < 4; ++k) {
        bool pr = (vals[k] >= lo);
        unsigned long long bal = __ballot(pr);
        if (bal) {
          unsigned wcnt = (unsigned)__popcll(bal);
          unsigned basep = 0u;
          if (lane == 0) basep = atomicAdd(&sh_cnt, wcnt);
          basep = __shfl(basep, 0, 64);
          if (pr) {
            unsigned posn =
                basep + (unsigned)__popcll(bal & ((1ull << lane) - 1ull));
            sh_cand[posn] = vals[k];
          }
        }
      }
    }
    __syncthreads();

    // ---- 5. single-wave register top-11 ----
    if (wid == 0) {
      unsigned v0[6];                           // 6*64 = 384 = CAND_MAX
#pragma unroll
      for (int j = 0; j < 6; ++j) {
        unsigned idx = (unsigned)lane + 64u * j;
        v0[j] = (idx < c) ? sh_cand[idx] : 0u;
      }
      unsigned ans = 0u;
      for (int r = 0; r < 11; ++r) {
        unsigned lmx = v0[0];
#pragma unroll
        for (int j = 1; j < 6; ++j) lmx = max(lmx, v0[j]);
        unsigned wm = lmx;
#pragma unroll
        for (int off = 32; off >= 1; off >>= 1)
          wm = max(wm, __shfl_xor(wm, off, 64));
        ans = wm;
        if (r < 10) {
          unsigned long long bal = __ballot(lmx == wm);
          int first = (int)__ffsll((long long)bal) - 1;
          if (lane == first) {  // remove ONE instance of wm
            bool rm = false;
#pragma unroll
            for (int j = 0; j < 6; ++j) {
              if (!rm && v0[j] == wm) { v0[j] = 0u; rm = true; }
            }
          }
        }
      }
      if (lane == 0) sh_e11 = ans;
    }
    __syncthreads();
    E11 = sh_e11;
  }

  // ---- 6. whitelist gather accumulate + block reduce ----
  float lm[8];
#pragma unroll
  for (int l = 0; l < 8; ++l) lm[l] = NEGF;
  unsigned pmask = 0u;  // bits0-7: label present; bits8-15: label has positive
  if (h0) {
    unsigned mk = ent0 & 255u;
    pmask |= mk;
    if (gy0 > 0.0f) pmask |= (mk << 8);
#pragma unroll
    for (int l = 0; l < 8; ++l)
      if ((mk >> l) & 1u) lm[l] = fmaxf(lm[l], gx0);
  }
  if (h1) {
    unsigned mk = ent1 & 255u;
    pmask |= mk;
    if (gy1 > 0.0f) pmask |= (mk << 8);
#pragma unroll
    for (int l = 0; l < 8; ++l)
      if ((mk >> l) & 1u) lm[l] = fmaxf(lm[l], gx1);
  }
  // safety net (nu <= ~400 here; loop normally never runs)
  for (unsigned e = (unsigned)tid + 512u; e < nu; e += 256u) {
    unsigned ent = ents[e];
    unsigned mk = ent & 255u;
    float xv = x[base + (ent >> 8)];
    float yv = y[base + (ent >> 8)];
    pmask |= mk;
    if (yv > 0.0f) pmask |= (mk << 8);
#pragma unroll
    for (int l = 0; l < 8; ++l)
      if ((mk >> l) & 1u) lm[l] = fmaxf(lm[l], xv);
  }
#pragma unroll
  for (int off = 32; off >= 1; off >>= 1) {
    pmask |= __shfl_xor(pmask, off, 64);
#pragma unroll
    for (int l = 0; l < 8; ++l) lm[l] = fmaxf(lm[l], __shfl_xor(lm[l], off, 64));
  }
  if (lane == 0) {
#pragma unroll
    for (int l = 0; l < 8; ++l) sh_wl[wid][l] = lm[l];
    sh_wl[wid][8] = __uint_as_float(pmask);
  }
  __syncthreads();

  // ---- 7. epilogue on thread 0: per-row partial ----
  if (tid == 0) {
    float LM[8];
    unsigned PM = 0u;
#pragma unroll
    for (int l = 0; l < 8; ++l) LM[l] = NEGF;
    for (int w = 0; w < 4; ++w) {
#pragma unroll
      for (int l = 0; l < 8; ++l) LM[l] = fmaxf(LM[l], sh_wl[w][l]);
      PM |= __float_as_uint(sh_wl[w][8]);
    }
    unsigned PR = PM & 255u, PO = (PM >> 8) & 255u;
    float thres = fmaxf(sigm(dec_u(E11)), 0.5f);
    float cmax = NEGF, imax = NEGF, umax = NEGF;
#pragma unroll
    for (int l = 0; l < 8; ++l) {
      if ((PR >> l) & 1u) {
        float ml = sigm(LM[l]);
        umax = fmaxf(umax, ml);
        if ((PO >> l) & 1u) cmax = fmaxf(cmax, ml);
        else imax = fmaxf(imax, ml);
      }
    }
    bool anyc = (PO != 0u);
    bool anyi = (PO != 255u);  // L == 8 labels always exist
    float x1 = anyc ? cmax : thres;
    float x2 = anyc ? (anyi ? fmaxf(imax, thres) : thres)
                    : ((nu > 0u) ? umax : NEGF);
    float coef = anyc ? 1.0f : 0.5f;
    float dd = x2 - x1 + 0.1f;
    float rank = ((dd > 0.0f) ? 2.0f : 1.0f) * sigm(10.0f * dd);
    partials[b] = coef * rank;
  }
}

__global__ void final_reduce(const float* __restrict__ partials,
                             float* __restrict__ out) {
  __shared__ float sh[4];
  const int tid = threadIdx.x;
  const int lane = tid & 63;
  const int wid = tid >> 6;
  float s = 0.0f;
  for (int i = tid; i < BB; i += 256) s += partials[i];
#pragma unroll
  for (int off = 32; off >= 1; off >>= 1) s += __shfl_xor(s, off, 64);
  if (lane == 0) sh[wid] = s;
  __syncthreads();
  if (tid == 0) out[0] = (sh[0] + sh[1] + sh[2] + sh[3]) * (1.0f / (float)BB);
}

extern "C" void kernel_launch(void* const* d_in, const int* in_sizes, int n_in,
                              void* d_out, int out_size, void* d_ws,
                              size_t ws_size, hipStream_t stream) {
  const float* x = (const float*)d_in[0];
  const float* y = (const float*)d_in[1];
  // d_in[2] (y_neg) is faithfully ignored — it never affects the loss.
  const unsigned char* wl = (const unsigned char*)d_in[3];
  float* out = (float*)d_out;
  unsigned* wsu = (unsigned*)d_ws;
  float* partials = (float*)((char*)d_ws + WS_PARTIALS_OFF);

  hipMemsetAsync(d_ws, 0, 16, stream);  // zero wsu[0..3]
  wl_sniff<<<64, 256, 0, stream>>>((const unsigned*)wl, wsu);
  wl_compact<<<(CC + 255) / 256, 256, 0, stream>>>(wl, wsu);
  loss_kernel<<<BB, 256, 0, stream>>>(x, y, wsu, partials);
  final_reduce<<<1, 256, 0, stream>>>(partials, out);
}